// Round 9
// baseline (247.554 us; speedup 1.0000x reference)
//
#include <hip/hip_runtime.h>
#include <hip/hip_bf16.h>

#define BB 4
#define LL 2048
#define DD 512
#define DKK 256

typedef __bf16 bf16;
typedef __bf16 bf16x4 __attribute__((ext_vector_type(4)));
typedef __bf16 bf16x8 __attribute__((ext_vector_type(8)));
typedef float f32x4 __attribute__((ext_vector_type(4)));

__device__ __forceinline__ void async_ld16(const bf16* g, bf16* l) {
    __builtin_amdgcn_global_load_lds(
        (const __attribute__((address_space(1))) void*)g,
        (__attribute__((address_space(3))) void*)l, 16, 0, 0);
}

// fused bf16 conversion of the three [B,L,D] activations (one launch)
__global__ void conv3_f32_bf16(const float* __restrict__ a, const float* __restrict__ bq,
                               const float* __restrict__ c,
                               bf16* __restrict__ oa, bf16* __restrict__ ob,
                               bf16* __restrict__ oc, int n4) {
    const float* in = (blockIdx.y == 0) ? a : (blockIdx.y == 1) ? bq : c;
    bf16* out = (blockIdx.y == 0) ? oa : (blockIdx.y == 1) ? ob : oc;
    int i = blockIdx.x * 256 + threadIdx.x;
    if (i < n4) {
        f32x4 v = *(const f32x4*)(in + (size_t)i * 4);
        bf16x4 o;
        #pragma unroll
        for (int j = 0; j < 4; ++j) o[j] = (bf16)v[j];
        *(bf16x4*)(out + (size_t)i * 4) = o;
    }
}

// merged prep: E conversion + Wq/Wk/Wv transposes in one launch (blockIdx.y)
__global__ void prep_misc(const float* __restrict__ E, const float* __restrict__ Wq,
                          const float* __restrict__ Wk, const float* __restrict__ Wv,
                          bf16* __restrict__ Eb, bf16* __restrict__ WqT,
                          bf16* __restrict__ WkT, bf16* __restrict__ WvT) {
    int y = blockIdx.y;
    int idx = blockIdx.x * 256 + threadIdx.x;
    if (y == 0) {
        if (idx < (LL * DKK) / 4) {
            f32x4 v = *(const f32x4*)(E + (size_t)idx * 4);
            bf16x4 o;
            #pragma unroll
            for (int j = 0; j < 4; ++j) o[j] = (bf16)v[j];
            *(bf16x4*)(Eb + (size_t)idx * 4) = o;
        }
    } else if (y == 1) {
        if (idx < DD * DKK) { int r = idx / DKK, c = idx % DKK; WqT[(size_t)c * DD + r] = (bf16)Wq[idx]; }
    } else if (y == 2) {
        if (idx < DD * DKK) { int r = idx / DKK, c = idx % DKK; WkT[(size_t)c * DD + r] = (bf16)Wk[idx]; }
    } else {
        if (idx < DD * DD)  { int r = idx / DD,  c = idx % DD;  WvT[(size_t)c * DD + r] = (bf16)Wv[idx]; }
    }
}

// Merged Q/K/V projection GEMM: one 512-block full-GPU launch (R15-proven).
__launch_bounds__(256, 2)
__global__ void gemm_qkv(const bf16* __restrict__ Xq, const bf16* __restrict__ WqT,
                         bf16* __restrict__ Qw,
                         const bf16* __restrict__ Xk, const bf16* __restrict__ WkT,
                         bf16* __restrict__ Kw,
                         const bf16* __restrict__ Xv, const bf16* __restrict__ WvT,
                         bf16* __restrict__ Vt)
{
    __shared__ bf16 Als[128 * 32];
    __shared__ bf16 Bls[128 * 32];
    __shared__ bf16 tbuf[64 * 136];

    int tid  = threadIdx.x;
    int lane = tid & 63;
    int wid  = tid >> 6;
    int l15  = lane & 15;
    int quad = lane >> 4;

    int bid  = blockIdx.x;
    int mode = (bid < 128) ? 0 : (bid < 256) ? 1 : 2;
    int idx  = bid - ((mode == 0) ? 0 : (mode == 1) ? 128 : 256);
    int nb   = (mode == 2) ? 4 : 2;
    int gx = idx % nb;
    int gy = idx / nb;
    int N  = (mode == 2) ? DD : DKK;
    const bf16* A  = (mode == 0) ? Xq  : (mode == 1) ? Xk  : Xv;
    const bf16* Bw = (mode == 0) ? WqT : (mode == 1) ? WkT : WvT;
    const int K = DD;

    const bf16* Ab = A + (size_t)gy * 128 * K;
    const bf16* Bb = Bw + (size_t)gx * 128 * K;

    int rl = lane >> 2;
    int sl = lane & 3;
    int half = wid & 1;
    const bf16* gsrc = (wid < 2) ? Ab : Bb;
    bf16* ldst = (wid < 2) ? Als : Bls;

    const bf16* gptr[4];
    #pragma unroll
    for (int u = 0; u < 4; ++u) {
        int inst = half * 4 + u;
        int row  = inst * 16 + rl;
        int c    = (sl - (row >> 1)) & 3;
        gptr[u] = gsrc + (size_t)row * K + c * 8;
    }

    f32x4 acc[4][4];
    #pragma unroll
    for (int i = 0; i < 4; ++i)
        #pragma unroll
        for (int j = 0; j < 4; ++j) acc[i][j] = 0;

    for (int k0 = 0; k0 < K; k0 += 32) {
        #pragma unroll
        for (int u = 0; u < 4; ++u) {
            async_ld16(gptr[u], ldst + (half * 4 + u) * 512);
            gptr[u] += 32;
        }
        __syncthreads();
        bf16x8 fA[4], fB[4];
        #pragma unroll
        for (int rt = 0; rt < 4; ++rt) {
            int row = (wid & 1) * 64 + rt * 16 + l15;
            int s   = (quad + (row >> 1)) & 3;
            fA[rt] = *(const bf16x8*)&Als[row * 32 + s * 8];
        }
        #pragma unroll
        for (int ct = 0; ct < 4; ++ct) {
            int col = (wid >> 1) * 64 + ct * 16 + l15;
            int s   = (quad + (col >> 1)) & 3;
            fB[ct] = *(const bf16x8*)&Bls[col * 32 + s * 8];
        }
        #pragma unroll
        for (int rt = 0; rt < 4; ++rt)
            #pragma unroll
            for (int ct = 0; ct < 4; ++ct)
                acc[rt][ct] = __builtin_amdgcn_mfma_f32_16x16x32_bf16(
                                  fA[rt], fB[ct], acc[rt][ct], 0, 0, 0);
        __syncthreads();
    }

    if (mode == 2) {
        #pragma unroll
        for (int p = 0; p < 2; ++p) {
            if ((wid >> 1) == p) {
                #pragma unroll
                for (int rt = 0; rt < 4; ++rt)
                    #pragma unroll
                    for (int ct = 0; ct < 4; ++ct)
                        #pragma unroll
                        for (int r = 0; r < 4; ++r)
                            tbuf[(ct * 16 + l15) * 136
                                 + (wid & 1) * 64 + rt * 16 + quad * 4 + r]
                                = (bf16)acc[rt][ct][r];
            }
            __syncthreads();
            int row = tid >> 2, c0 = (tid & 3) * 32;
            bf16* dst = Vt + (size_t)(gx * 128 + p * 64 + row) * (BB * LL)
                           + (size_t)gy * 128 + c0;
            #pragma unroll
            for (int q = 0; q < 4; ++q)
                *(bf16x8*)(dst + q * 8) = *(const bf16x8*)&tbuf[row * 136 + c0 + q * 8];
            __syncthreads();
        }
    } else {
        bf16* Cb = (mode == 0) ? Qw : Kw;
        int m0 = gy * 128 + (wid & 1) * 64;
        int n0 = gx * 128 + (wid >> 1) * 64;
        #pragma unroll
        for (int rt = 0; rt < 4; ++rt)
            #pragma unroll
            for (int ct = 0; ct < 4; ++ct)
                #pragma unroll
                for (int r = 0; r < 4; ++r) {
                    int m = m0 + rt * 16 + quad * 4 + r;
                    int n = n0 + ct * 16 + l15;
                    Cb[(size_t)m * N + n] = (bf16)acc[rt][ct][r];
                }
    }
}

// Srel GEMM (skewed scatter epilogue), unchanged.
__launch_bounds__(256, 2)
__global__ void gemm_srel(const bf16* __restrict__ A, const bf16* __restrict__ B,
                          bf16* __restrict__ C, long aStride, long cStride)
{
    __shared__ bf16 Als[128 * 32];
    __shared__ bf16 Bls[128 * 32];

    int tid  = threadIdx.x;
    int lane = tid & 63;
    int wid  = tid >> 6;
    int l15  = lane & 15;
    int quad = lane >> 4;
    const int N = LL, K = DKK;
    int nb = N >> 7;
    int gx = blockIdx.x % nb;
    int gy = blockIdx.x / nb;

    const bf16* Ab = A + (size_t)blockIdx.y * aStride + (size_t)gy * 128 * K;
    const bf16* Bb = B + (size_t)gx * 128 * K;

    int rl = lane >> 2;
    int sl = lane & 3;
    int half = wid & 1;
    const bf16* gsrc = (wid < 2) ? Ab : Bb;
    bf16* ldst = (wid < 2) ? Als : Bls;

    const bf16* gptr[4];
    #pragma unroll
    for (int u = 0; u < 4; ++u) {
        int inst = half * 4 + u;
        int row  = inst * 16 + rl;
        int c    = (sl - (row >> 1)) & 3;
        gptr[u] = gsrc + (size_t)row * K + c * 8;
    }

    f32x4 acc[4][4];
    #pragma unroll
    for (int i = 0; i < 4; ++i)
        #pragma unroll
        for (int j = 0; j < 4; ++j) acc[i][j] = 0;

    for (int k0 = 0; k0 < K; k0 += 32) {
        #pragma unroll
        for (int u = 0; u < 4; ++u) {
            async_ld16(gptr[u], ldst + (half * 4 + u) * 512);
            gptr[u] += 32;
        }
        __syncthreads();
        bf16x8 fA[4], fB[4];
        #pragma unroll
        for (int rt = 0; rt < 4; ++rt) {
            int row = (wid & 1) * 64 + rt * 16 + l15;
            int s   = (quad + (row >> 1)) & 3;
            fA[rt] = *(const bf16x8*)&Als[row * 32 + s * 8];
        }
        #pragma unroll
        for (int ct = 0; ct < 4; ++ct) {
            int col = (wid >> 1) * 64 + ct * 16 + l15;
            int s   = (quad + (col >> 1)) & 3;
            fB[ct] = *(const bf16x8*)&Bls[col * 32 + s * 8];
        }
        #pragma unroll
        for (int rt = 0; rt < 4; ++rt)
            #pragma unroll
            for (int ct = 0; ct < 4; ++ct)
                acc[rt][ct] = __builtin_amdgcn_mfma_f32_16x16x32_bf16(
                                  fA[rt], fB[ct], acc[rt][ct], 0, 0, 0);
        __syncthreads();
    }

    bf16* Cb = C + (size_t)blockIdx.y * cStride;
    int m0 = gy * 128 + (wid & 1) * 64;
    int n0 = gx * 128 + (wid >> 1) * 64;
    #pragma unroll
    for (int rt = 0; rt < 4; ++rt)
        #pragma unroll
        for (int ct = 0; ct < 4; ++ct)
            #pragma unroll
            for (int r = 0; r < 4; ++r) {
                int row = m0 + rt * 16 + quad * 4 + r;
                int c   = n0 + ct * 16 + l15;
                bool lower = (c >= LL - 1 - row);
                int dr = lower ? row : row - 1;
                int dc = lower ? c - (LL - 1 - row) : c + row + 1;
                if (lower || row >= 1)
                    Cb[(size_t)dr * LL + dc] = (bf16)acc[rt][ct][r];
            }
}

// Fused attention R16: 8-WAVE BLOCKS (512 threads) -- 16 waves/CU = 4/SIMD,
// double R15's occupancy at the same ~75KB LDS (2 blocks/CU).  Three rounds of
// phase restructuring were neutral; the counters (Occupancy 19%, MfmaUtil 15%,
// VALUBusy 26%) say waves park at barriers with nothing to fill the SIMD.
// Work split:
//   QK: wave (qh=wid&1, jh=wid>>1): S[q=qh*16+l15][j=jh*16+quad*4+r], 8 MFMA.
//   PV: wave owns d-slice [32*wid,+32) x all 32 q, 8 MFMA -- chosen so V
//       staging is WAVE-LOCAL (stager == sole reader).
// Staging ownership: K rows [8w,+8) (pair-shared with consumers -> K(i+1) is
// issued POST-b2 after all kf reads, published by the vmcnt(0) pre-b3);
// V rows [32w,+32) (wave-local, issued in PV(i) after own lgkm0, full-iter
// flight).  srel: reg-loaded in QK(i), LDS-staged in softmax(i) (compiler-
// tracked wait), consumed v-compute(i+1).  ONE manual wait/iter: vmcnt(0)
// pre-b3 (publishes K(i+1), drains V(i)).  Hazards: Ps/aSt write post-b2(i),
// read PV(i), next write post-b2(i+1) [b2 guards]; SrelL read pre-b2, write
// post-b2; pmax write pre-b2, read post-b2, next write after b3; Klds DMA
// post-b2 vs reads pre-b2 [b2], landing pre-b3 vs reads post-b3 [b3].
__launch_bounds__(512, 4)
__global__ void attn_kernel(const bf16* __restrict__ Qw, const bf16* __restrict__ Kw,
                            const bf16* __restrict__ Vt, const bf16* __restrict__ Srel,
                            float* __restrict__ out)
{
    __shared__ bf16  Klds[64 * 256];      // 32 KB: rows j, 32 chunks of 8, rotated
    __shared__ bf16  Vlds[256 * 64];      // 32 KB: rows d, 8 chunks of 8, rotated
    __shared__ bf16  SrelL[32 * 72];      // 4.5 KB
    __shared__ bf16  Ps[32][72];          // 4.5 KB
    __shared__ float pmax[32][4];         // per-(q, jh) max partials; reused for l
    __shared__ float aSt[32];

    int tid  = threadIdx.x;
    int lane = tid & 63;
    int wid  = tid >> 6;          // 0..7
    int l15  = lane & 15;
    int quad = lane >> 4;
    int qh   = wid & 1;           // QK q-half
    int jh   = wid >> 1;          // QK j-quarter (0..3)

    int xcd = blockIdx.x & 7;
    int b   = xcd >> 1;
    int dh  = xcd & 1;
    int i0  = (blockIdx.x >> 3) * 32;

    const bf16* Qb = Qw + (size_t)b * LL * DKK;
    const bf16* Kb = Kw + (size_t)b * LL * DKK;
    const bf16* Sb = Srel + (size_t)b * LL * LL;
    const bf16* Vb = Vt + (size_t)(dh * 256) * (BB * LL) + (size_t)b * LL;

    // staging pointers: K rows [8w,+8) (4 inst, 2 rows each);
    //                   V rows [32w,+32) (4 inst, 8 rows each)
    const bf16* kptr[4];
    const bf16* vptr[4];
    #pragma unroll
    for (int u = 0; u < 4; ++u) {
        int kinst = wid * 4 + u;
        int j_ = kinst * 2 + (lane >> 5);
        int ck = ((lane & 31) - j_) & 31;
        kptr[u] = Kb + (size_t)j_ * DKK + ck * 8;
        int d_ = kinst * 8 + (lane >> 3);
        int cv = ((lane & 7) - d_) & 7;
        vptr[u] = Vb + (size_t)d_ * (BB * LL) + cv * 8;
    }

    // Q fragments: this wave's 16 q-rows (qh half), 8 k-slices
    bf16x8 Qreg[8];
    #pragma unroll
    for (int ks = 0; ks < 8; ++ks)
        Qreg[ks] = *(const bf16x8*)(Qb + (size_t)(i0 + qh * 16 + l15) * DKK
                                    + ks * 32 + quad * 8);

    f32x4 accO[2][2];
    #pragma unroll
    for (int rt = 0; rt < 2; ++rt)
        #pragma unroll
        for (int nt = 0; nt < 2; ++nt) accO[rt][nt] = 0;

    float mreg = -1e30f;      // running max for q = qh*16+l15 (all jh consistent)
    float lreg = 0.f;         // this wave's partial l over its jh quarter

    // ---- prologue: srel(0), K(0), V(0), SrelL(0); drain all; publish ----
    int srowl = tid >> 4;             // 0..31
    int scol  = (tid & 15) * 4;       // 0..60
    const bf16* sPtr = Sb + (size_t)(i0 + srowl) * LL + scol;
    bf16x4 srelNext = *(const bf16x4*)sPtr;
    sPtr += 64;
    __builtin_amdgcn_sched_barrier(0);
    #pragma unroll
    for (int u = 0; u < 4; ++u) {
        async_ld16(kptr[u], Klds + (wid * 4 + u) * 512);
        kptr[u] += 64 * DKK;
        async_ld16(vptr[u], Vlds + (wid * 4 + u) * 512);
        vptr[u] += 64;
    }
    __builtin_amdgcn_sched_barrier(0);
    *(bf16x4*)&SrelL[srowl * 72 + scol] = srelNext;
    asm volatile("s_waitcnt vmcnt(0) lgkmcnt(0)\ns_barrier" ::: "memory");

    int jrow = jh * 16 + l15;

    for (int j0 = 0; j0 < LL; j0 += 64) {
        bool notlast = (j0 + 64 < LL);

        // ===== QK phase (Klds/Vlds/SrelL published by previous barrier) =====
        bf16x8 kf[8];
        #pragma unroll
        for (int ks = 0; ks < 8; ++ks) {
            int cp = (ks * 4 + quad + jrow) & 31;
            kf[ks] = *(const bf16x8*)&Klds[jrow * 256 + cp * 8];
        }
        if (notlast) {                       // srel(i+1) reg-load: QK->softmax flight
            srelNext = *(const bf16x4*)sPtr;
            sPtr += 64;
        }
        __builtin_amdgcn_sched_barrier(0);
        f32x4 s0 = 0;
        __builtin_amdgcn_s_setprio(1);
        #pragma unroll
        for (int ks = 0; ks < 8; ++ks)
            s0 = __builtin_amdgcn_mfma_f32_16x16x32_bf16(kf[ks], Qreg[ks], s0, 0, 0, 0);
        __builtin_amdgcn_s_setprio(0);

        // v-compute: srel add (tile i from SrelL) + mask + scale
        bf16x4 sr = *(const bf16x4*)&SrelL[(qh * 16 + l15) * 72 + jh * 16 + quad * 4];
        int iq = i0 + qh * 16 + l15;
        int jb = j0 + jh * 16 + quad * 4;
        float v[4];
        #pragma unroll
        for (int r = 0; r < 4; ++r) {
            float a = (jb + r == iq + 1) ? 0.f : (float)sr[r];
            v[r] = (s0[r] + a) * 0.0625f;
        }
        float m0 = fmaxf(fmaxf(v[0], v[1]), fmaxf(v[2], v[3]));
        m0 = fmaxf(m0, __shfl_xor(m0, 16));
        m0 = fmaxf(m0, __shfl_xor(m0, 32));
        if (quad == 0) pmax[qh * 16 + l15][jh] = m0;
        asm volatile("s_waitcnt lgkmcnt(0)\ns_barrier" ::: "memory");   // b2

        // ===== softmax phase =====
        if (notlast) {                       // K(i+1): all kf reads done (b2)
            #pragma unroll
            for (int u = 0; u < 4; ++u) {
                async_ld16(kptr[u], Klds + (wid * 4 + u) * 512);
                kptr[u] += 64 * DKK;
            }
        }
        __builtin_amdgcn_sched_barrier(0);
        f32x4 pm = *(const f32x4*)&pmax[qh * 16 + l15][0];
        float mf = fmaxf(fmaxf(fmaxf(pm[0], pm[1]), fmaxf(pm[2], pm[3])), mreg);
        float alpha = __expf(mreg - mf);
        mreg = mf;
        if (notlast)                         // SrelL <- srel(i+1); compiler waits load
            *(bf16x4*)&SrelL[srowl * 72 + scol] = srelNext;
        float ps = 0.f;
        bf16x4 pv;
        #pragma unroll
        for (int r = 0; r < 4; ++r) {
            float e = __expf(v[r] - mf);
            ps += e;
            pv[r] = (bf16)e;
        }
        ps += __shfl_xor(ps, 16);
        ps += __shfl_xor(ps, 32);
        lreg = alpha * lreg + ps;
        *(bf16x4*)&Ps[qh * 16 + l15][jh * 16 + quad * 4] = pv;
        if (wid < 2 && quad == 0) aSt[qh * 16 + l15] = alpha;
        // publish K(i+1) (pair-shared) + drain V(i) (wave-local), then barrier
        asm volatile("s_waitcnt vmcnt(0) lgkmcnt(0)\ns_barrier" ::: "memory");  // b3

        // ===== PV phase: O += P(i)·V(i) on d-slice [32*wid,+32) =====
        bf16x8 aF[2][2];
        #pragma unroll
        for (int rt = 0; rt < 2; ++rt)
            #pragma unroll
            for (int kk = 0; kk < 2; ++kk)
                aF[rt][kk] = *(const bf16x8*)&Ps[rt * 16 + l15][kk * 32 + quad * 8];
        float ar[2][4];
        #pragma unroll
        for (int rt = 0; rt < 2; ++rt)
            #pragma unroll
            for (int r = 0; r < 4; ++r) ar[rt][r] = aSt[rt * 16 + quad * 4 + r];
        bf16x8 vf[2][2];
        #pragma unroll
        for (int nt = 0; nt < 2; ++nt) {
            int dd = wid * 32 + nt * 16 + l15;
            int c0 = (quad + dd) & 7;
            int c1 = (4 + quad + dd) & 7;
            vf[nt][0] = *(const bf16x8*)&Vlds[dd * 64 + c0 * 8];
            vf[nt][1] = *(const bf16x8*)&Vlds[dd * 64 + c1 * 8];
        }
        asm volatile("s_waitcnt lgkmcnt(0)" ::: "memory");  // own vf/aF reads done
        __builtin_amdgcn_sched_barrier(0);
        if (notlast) {                       // V(i+1): wave-local rows, WAR-safe
            #pragma unroll
            for (int u = 0; u < 4; ++u) {
                async_ld16(vptr[u], Vlds + (wid * 4 + u) * 512);
                vptr[u] += 64;
            }
        }
        __builtin_amdgcn_sched_barrier(0);
        __builtin_amdgcn_s_setprio(1);
        #pragma unroll
        for (int nt = 0; nt < 2; ++nt)
            #pragma unroll
            for (int rt = 0; rt < 2; ++rt) {
                f32x4 o = accO[rt][nt];
                o[0] *= ar[rt][0]; o[1] *= ar[rt][1];
                o[2] *= ar[rt][2]; o[3] *= ar[rt][3];
                o = __builtin_amdgcn_mfma_f32_16x16x32_bf16(aF[rt][0], vf[nt][0], o, 0, 0, 0);
                o = __builtin_amdgcn_mfma_f32_16x16x32_bf16(aF[rt][1], vf[nt][1], o, 0, 0, 0);
                accO[rt][nt] = o;
            }
        __builtin_amdgcn_s_setprio(0);
        // no trailing barrier: Ps/aSt WAR guarded by b2(i+1); Vlds wave-local;
        // Klds WAR (next DMA post-b2(i+1)) vs kf reads (pre-b2(i+1)) guarded.
    }

    // ---- final l merge: sum 4 jh-partials per q ----
    if (quad == 0) pmax[qh * 16 + l15][jh] = lreg;
    asm volatile("s_waitcnt lgkmcnt(0)\ns_barrier" ::: "memory");
    float lr[2][4];
    #pragma unroll
    for (int rt = 0; rt < 2; ++rt)
        #pragma unroll
        for (int r = 0; r < 4; ++r) {
            f32x4 lp = *(const f32x4*)&pmax[rt * 16 + quad * 4 + r][0];
            lr[rt][r] = 1.f / (lp[0] + lp[1] + lp[2] + lp[3]);
        }
    #pragma unroll
    for (int rt = 0; rt < 2; ++rt)
        #pragma unroll
        for (int nt = 0; nt < 2; ++nt)
            #pragma unroll
            for (int r = 0; r < 4; ++r) {
                int i = i0 + rt * 16 + quad * 4 + r;
                int d = dh * 256 + wid * 32 + nt * 16 + l15;
                out[((size_t)b * LL + i) * DD + d] = accO[rt][nt][r] * lr[rt][r];
            }
}

extern "C" void kernel_launch(void* const* d_in, const int* in_sizes, int n_in,
                              void* d_out, int out_size, void* d_ws, size_t ws_size,
                              hipStream_t stream) {
    const float* inQ = (const float*)d_in[0];
    const float* inK = (const float*)d_in[1];
    const float* inV = (const float*)d_in[2];
    const float* Wq  = (const float*)d_in[3];
    const float* Wk  = (const float*)d_in[4];
    const float* Wv  = (const float*)d_in[5];
    const float* E   = (const float*)d_in[6];
    float* out = (float*)d_out;

    char* ws = (char*)d_ws;
    bf16* Qw   = (bf16*)(ws);                         // 4 MB  [B*L][DK]
    bf16* Kw   = (bf16*)(ws + ((size_t)4  << 20));    // 4 MB  [B*L][DK]
    bf16* Vt   = (bf16*)(ws + ((size_t)8  << 20));    // 8 MB  [D][B*L]
    bf16* SrelW= (bf16*)(ws + ((size_t)16 << 20));    // 32 MB [B,L,L] skewed
    bf16* Xq   = (bf16*)(ws + ((size_t)16 << 20));    // 8 MB  (transient)
    bf16* Xk   = (bf16*)(ws + ((size_t)24 << 20));    // 8 MB
    bf16* Xv   = (bf16*)(ws + ((size_t)32 << 20));    // 8 MB
    bf16* WqT  = (bf16*)(ws + ((size_t)48 << 20));            // [DK][D]
    bf16* WkT  = (bf16*)(ws + ((size_t)48 << 20) + 262144);   // [DK][D]
    bf16* WvT  = (bf16*)(ws + ((size_t)48 << 20) + 524288);   // [D][D]
    bf16* Eb   = (bf16*)(ws + ((size_t)49 << 20));            // [L][DK]

    conv3_f32_bf16<<<dim3(4096, 3), 256, 0, stream>>>(inQ, inK, inV, Xq, Xk, Xv,
                                                      (BB * LL * DD) / 4);
    prep_misc<<<dim3(1024, 4), 256, 0, stream>>>(E, Wq, Wk, Wv, Eb, WqT, WkT, WvT);

    // Q, K, V projections in ONE full-GPU launch (512 blocks)
    gemm_qkv<<<512, 256, 0, stream>>>(Xq, WqT, Qw, Xk, WkT, Kw, Xv, WvT, Vt);
    // Srel (skewed) = skew(Q·E^T): per-batch M=N=2048 K=256
    gemm_srel<<<dim3(16 * 16, BB), 256, 0, stream>>>(Qw, Eb, SrelW,
                                                     (long)LL * DKK, (long)LL * LL);
    attn_kernel<<<dim3(BB * 64 * 2), 512, 0, stream>>>(Qw, Kw, Vt, SrelW, out);
}

// Round 10
// 221.675 us; speedup vs baseline: 1.1167x; 1.1167x over previous
//
#include <hip/hip_runtime.h>
#include <hip/hip_bf16.h>

#define BB 4
#define LL 2048
#define DD 512
#define DKK 256

typedef __bf16 bf16;
typedef __bf16 bf16x4 __attribute__((ext_vector_type(4)));
typedef __bf16 bf16x8 __attribute__((ext_vector_type(8)));
typedef float f32x4 __attribute__((ext_vector_type(4)));

__device__ __forceinline__ void async_ld16(const bf16* g, bf16* l) {
    __builtin_amdgcn_global_load_lds(
        (const __attribute__((address_space(1))) void*)g,
        (__attribute__((address_space(3))) void*)l, 16, 0, 0);
}

// fused bf16 conversion of the three [B,L,D] activations (one launch)
__global__ void conv3_f32_bf16(const float* __restrict__ a, const float* __restrict__ bq,
                               const float* __restrict__ c,
                               bf16* __restrict__ oa, bf16* __restrict__ ob,
                               bf16* __restrict__ oc, int n4) {
    const float* in = (blockIdx.y == 0) ? a : (blockIdx.y == 1) ? bq : c;
    bf16* out = (blockIdx.y == 0) ? oa : (blockIdx.y == 1) ? ob : oc;
    int i = blockIdx.x * 256 + threadIdx.x;
    if (i < n4) {
        f32x4 v = *(const f32x4*)(in + (size_t)i * 4);
        bf16x4 o;
        #pragma unroll
        for (int j = 0; j < 4; ++j) o[j] = (bf16)v[j];
        *(bf16x4*)(out + (size_t)i * 4) = o;
    }
}

// merged prep: E conversion + Wq/Wk/Wv transposes in one launch (blockIdx.y)
__global__ void prep_misc(const float* __restrict__ E, const float* __restrict__ Wq,
                          const float* __restrict__ Wk, const float* __restrict__ Wv,
                          bf16* __restrict__ Eb, bf16* __restrict__ WqT,
                          bf16* __restrict__ WkT, bf16* __restrict__ WvT) {
    int y = blockIdx.y;
    int idx = blockIdx.x * 256 + threadIdx.x;
    if (y == 0) {
        if (idx < (LL * DKK) / 4) {
            f32x4 v = *(const f32x4*)(E + (size_t)idx * 4);
            bf16x4 o;
            #pragma unroll
            for (int j = 0; j < 4; ++j) o[j] = (bf16)v[j];
            *(bf16x4*)(Eb + (size_t)idx * 4) = o;
        }
    } else if (y == 1) {
        if (idx < DD * DKK) { int r = idx / DKK, c = idx % DKK; WqT[(size_t)c * DD + r] = (bf16)Wq[idx]; }
    } else if (y == 2) {
        if (idx < DD * DKK) { int r = idx / DKK, c = idx % DKK; WkT[(size_t)c * DD + r] = (bf16)Wk[idx]; }
    } else {
        if (idx < DD * DD)  { int r = idx / DD,  c = idx % DD;  WvT[(size_t)c * DD + r] = (bf16)Wv[idx]; }
    }
}

// Merged Q/K/V projection GEMM, R17: BK=64 per barrier pair via double-buffered
// 32-wide sub-tiles.  Both sub-buffers staged (8 async_ld16/wave), ONE
// __syncthreads, 32 MFMAs (16 per sub-buffer), ONE __syncthreads.  Halves the
// barrier-drain rounds (16 -> 8 at K=512) -- the documented ~20% barrier stall
// dominates these short-K shapes.  Swizzle/fragment code per sub-buffer is
// byte-identical to the proven 32-wide layout.
__launch_bounds__(256, 2)
__global__ void gemm_qkv(const bf16* __restrict__ Xq, const bf16* __restrict__ WqT,
                         bf16* __restrict__ Qw,
                         const bf16* __restrict__ Xk, const bf16* __restrict__ WkT,
                         bf16* __restrict__ Kw,
                         const bf16* __restrict__ Xv, const bf16* __restrict__ WvT,
                         bf16* __restrict__ Vt)
{
    __shared__ bf16 Als[2][128 * 32];
    __shared__ bf16 Bls[2][128 * 32];
    __shared__ bf16 tbuf[64 * 136];

    int tid  = threadIdx.x;
    int lane = tid & 63;
    int wid  = tid >> 6;
    int l15  = lane & 15;
    int quad = lane >> 4;

    int bid  = blockIdx.x;
    int mode = (bid < 128) ? 0 : (bid < 256) ? 1 : 2;
    int idx  = bid - ((mode == 0) ? 0 : (mode == 1) ? 128 : 256);
    int nb   = (mode == 2) ? 4 : 2;
    int gx = idx % nb;
    int gy = idx / nb;
    int N  = (mode == 2) ? DD : DKK;
    const bf16* A  = (mode == 0) ? Xq  : (mode == 1) ? Xk  : Xv;
    const bf16* Bw = (mode == 0) ? WqT : (mode == 1) ? WkT : WvT;
    const int K = DD;

    const bf16* Ab = A + (size_t)gy * 128 * K;
    const bf16* Bb = Bw + (size_t)gx * 128 * K;

    int rl = lane >> 2;
    int sl = lane & 3;
    int half = wid & 1;
    const bf16* gsrc = (wid < 2) ? Ab : Bb;
    bf16* ldst0 = (wid < 2) ? Als[0] : Bls[0];
    bf16* ldst1 = (wid < 2) ? Als[1] : Bls[1];

    const bf16* gptr[4];
    #pragma unroll
    for (int u = 0; u < 4; ++u) {
        int inst = half * 4 + u;
        int row  = inst * 16 + rl;
        int c    = (sl - (row >> 1)) & 3;
        gptr[u] = gsrc + (size_t)row * K + c * 8;
    }

    f32x4 acc[4][4];
    #pragma unroll
    for (int i = 0; i < 4; ++i)
        #pragma unroll
        for (int j = 0; j < 4; ++j) acc[i][j] = 0;

    for (int k0 = 0; k0 < K; k0 += 64) {
        #pragma unroll
        for (int u = 0; u < 4; ++u) {
            async_ld16(gptr[u],      ldst0 + (half * 4 + u) * 512);
            async_ld16(gptr[u] + 32, ldst1 + (half * 4 + u) * 512);
            gptr[u] += 64;
        }
        __syncthreads();   // drains vmcnt(0): both sub-tiles staged
        #pragma unroll
        for (int h2 = 0; h2 < 2; ++h2) {
            bf16x8 fA[4], fB[4];
            #pragma unroll
            for (int rt = 0; rt < 4; ++rt) {
                int row = (wid & 1) * 64 + rt * 16 + l15;
                int s   = (quad + (row >> 1)) & 3;
                fA[rt] = *(const bf16x8*)&Als[h2][row * 32 + s * 8];
            }
            #pragma unroll
            for (int ct = 0; ct < 4; ++ct) {
                int col = (wid >> 1) * 64 + ct * 16 + l15;
                int s   = (quad + (col >> 1)) & 3;
                fB[ct] = *(const bf16x8*)&Bls[h2][col * 32 + s * 8];
            }
            #pragma unroll
            for (int rt = 0; rt < 4; ++rt)
                #pragma unroll
                for (int ct = 0; ct < 4; ++ct)
                    acc[rt][ct] = __builtin_amdgcn_mfma_f32_16x16x32_bf16(
                                      fA[rt], fB[ct], acc[rt][ct], 0, 0, 0);
        }
        __syncthreads();   // LDS reuse guard
    }

    if (mode == 2) {
        #pragma unroll
        for (int p = 0; p < 2; ++p) {
            if ((wid >> 1) == p) {
                #pragma unroll
                for (int rt = 0; rt < 4; ++rt)
                    #pragma unroll
                    for (int ct = 0; ct < 4; ++ct)
                        #pragma unroll
                        for (int r = 0; r < 4; ++r)
                            tbuf[(ct * 16 + l15) * 136
                                 + (wid & 1) * 64 + rt * 16 + quad * 4 + r]
                                = (bf16)acc[rt][ct][r];
            }
            __syncthreads();
            int row = tid >> 2, c0 = (tid & 3) * 32;
            bf16* dst = Vt + (size_t)(gx * 128 + p * 64 + row) * (BB * LL)
                           + (size_t)gy * 128 + c0;
            #pragma unroll
            for (int q = 0; q < 4; ++q)
                *(bf16x8*)(dst + q * 8) = *(const bf16x8*)&tbuf[row * 136 + c0 + q * 8];
            __syncthreads();
        }
    } else {
        bf16* Cb = (mode == 0) ? Qw : Kw;
        int m0 = gy * 128 + (wid & 1) * 64;
        int n0 = gx * 128 + (wid >> 1) * 64;
        #pragma unroll
        for (int rt = 0; rt < 4; ++rt)
            #pragma unroll
            for (int ct = 0; ct < 4; ++ct)
                #pragma unroll
                for (int r = 0; r < 4; ++r) {
                    int m = m0 + rt * 16 + quad * 4 + r;
                    int n = n0 + ct * 16 + l15;
                    Cb[(size_t)m * N + n] = (bf16)acc[rt][ct][r];
                }
    }
}

// Srel GEMM, R17: same BK=64 double-buffer (8 -> 4 barrier rounds at K=256).
// Skewed scatter epilogue unchanged.
__launch_bounds__(256, 2)
__global__ void gemm_srel(const bf16* __restrict__ A, const bf16* __restrict__ B,
                          bf16* __restrict__ C, long aStride, long cStride)
{
    __shared__ bf16 Als[2][128 * 32];
    __shared__ bf16 Bls[2][128 * 32];

    int tid  = threadIdx.x;
    int lane = tid & 63;
    int wid  = tid >> 6;
    int l15  = lane & 15;
    int quad = lane >> 4;
    const int N = LL, K = DKK;
    int nb = N >> 7;
    int gx = blockIdx.x % nb;
    int gy = blockIdx.x / nb;

    const bf16* Ab = A + (size_t)blockIdx.y * aStride + (size_t)gy * 128 * K;
    const bf16* Bb = B + (size_t)gx * 128 * K;

    int rl = lane >> 2;
    int sl = lane & 3;
    int half = wid & 1;
    const bf16* gsrc = (wid < 2) ? Ab : Bb;
    bf16* ldst0 = (wid < 2) ? Als[0] : Bls[0];
    bf16* ldst1 = (wid < 2) ? Als[1] : Bls[1];

    const bf16* gptr[4];
    #pragma unroll
    for (int u = 0; u < 4; ++u) {
        int inst = half * 4 + u;
        int row  = inst * 16 + rl;
        int c    = (sl - (row >> 1)) & 3;
        gptr[u] = gsrc + (size_t)row * K + c * 8;
    }

    f32x4 acc[4][4];
    #pragma unroll
    for (int i = 0; i < 4; ++i)
        #pragma unroll
        for (int j = 0; j < 4; ++j) acc[i][j] = 0;

    for (int k0 = 0; k0 < K; k0 += 64) {
        #pragma unroll
        for (int u = 0; u < 4; ++u) {
            async_ld16(gptr[u],      ldst0 + (half * 4 + u) * 512);
            async_ld16(gptr[u] + 32, ldst1 + (half * 4 + u) * 512);
            gptr[u] += 64;
        }
        __syncthreads();
        #pragma unroll
        for (int h2 = 0; h2 < 2; ++h2) {
            bf16x8 fA[4], fB[4];
            #pragma unroll
            for (int rt = 0; rt < 4; ++rt) {
                int row = (wid & 1) * 64 + rt * 16 + l15;
                int s   = (quad + (row >> 1)) & 3;
                fA[rt] = *(const bf16x8*)&Als[h2][row * 32 + s * 8];
            }
            #pragma unroll
            for (int ct = 0; ct < 4; ++ct) {
                int col = (wid >> 1) * 64 + ct * 16 + l15;
                int s   = (quad + (col >> 1)) & 3;
                fB[ct] = *(const bf16x8*)&Bls[h2][col * 32 + s * 8];
            }
            #pragma unroll
            for (int rt = 0; rt < 4; ++rt)
                #pragma unroll
                for (int ct = 0; ct < 4; ++ct)
                    acc[rt][ct] = __builtin_amdgcn_mfma_f32_16x16x32_bf16(
                                      fA[rt], fB[ct], acc[rt][ct], 0, 0, 0);
        }
        __syncthreads();
    }

    bf16* Cb = C + (size_t)blockIdx.y * cStride;
    int m0 = gy * 128 + (wid & 1) * 64;
    int n0 = gx * 128 + (wid >> 1) * 64;
    #pragma unroll
    for (int rt = 0; rt < 4; ++rt)
        #pragma unroll
        for (int ct = 0; ct < 4; ++ct)
            #pragma unroll
            for (int r = 0; r < 4; ++r) {
                int row = m0 + rt * 16 + quad * 4 + r;
                int c   = n0 + ct * 16 + l15;
                bool lower = (c >= LL - 1 - row);
                int dr = lower ? row : row - 1;
                int dc = lower ? c - (LL - 1 - row) : c + row + 1;
                if (lower || row >= 1)
                    Cb[(size_t)dr * LL + dc] = (bf16)acc[rt][ct][r];
            }
}

// Fused attention: REVERTED to the best-measured R13 structure (86.4us).
// 4 waves / 256 threads, one-ahead split staging with counted vmcnt,
// pointer-increment staging addresses, Ss-LDS softmax.  (R14 in-reg softmax
// 87.9, R15 deferred-PV 89.4, R16 8-wave 115.9 -- all equal-or-worse; this
// decomposition's floor is ~86us and further attn restructuring is parked.)
__launch_bounds__(256, 2)
__global__ void attn_kernel(const bf16* __restrict__ Qw, const bf16* __restrict__ Kw,
                            const bf16* __restrict__ Vt, const bf16* __restrict__ Srel,
                            float* __restrict__ out)
{
    __shared__ bf16  Klds[64 * 256];      // rows j (64), 32 chunks of 8, rotated
    __shared__ bf16  Vlds[256 * 64];      // rows d (256), 8 chunks of 8, rotated
    __shared__ float Ss[32][68];
    __shared__ bf16  Ps[32][72];
    __shared__ float mSt[32], lSt[32], aSt[32];

    int tid  = threadIdx.x;
    int lane = tid & 63;
    int wid  = tid >> 6;
    int l15  = lane & 15;
    int quad = lane >> 4;

    int xcd = blockIdx.x & 7;          // XCD = blockIdx % 8 (round-robin dispatch)
    int b   = xcd >> 1;
    int dh  = xcd & 1;
    int i0  = (blockIdx.x >> 3) * 32;

    const bf16* Qb = Qw + (size_t)b * LL * DKK;
    const bf16* Kb = Kw + (size_t)b * LL * DKK;
    const bf16* Sb = Srel + (size_t)b * LL * LL;
    const bf16* Vb = Vt + (size_t)(dh * 256) * (BB * LL) + (size_t)b * LL;

    // persistent staging pointers (wave-local rows), bumped per iteration
    const bf16* kptr[8];
    const bf16* vptr[8];
    #pragma unroll
    for (int u = 0; u < 8; ++u) {
        int inst = wid * 8 + u;
        int j_ = inst * 2 + (lane >> 5);
        int ck = ((lane & 31) - j_) & 31;
        kptr[u] = Kb + (size_t)j_ * DKK + ck * 8;
        int d_ = inst * 8 + (lane >> 3);
        int cv = ((lane & 7) - d_) & 7;
        vptr[u] = Vb + (size_t)d_ * (BB * LL) + cv * 8;
    }

    bf16x8 Qreg[2][8];
    #pragma unroll
    for (int rt = 0; rt < 2; ++rt)
        #pragma unroll
        for (int ks = 0; ks < 8; ++ks)
            Qreg[rt][ks] = *(const bf16x8*)(Qb + (size_t)(i0 + rt * 16 + l15) * DKK
                                            + ks * 32 + quad * 8);

    if (tid < 32) { mSt[tid] = -1e30f; lSt[tid] = 0.f; }

    f32x4 accO[2][4];
    #pragma unroll
    for (int rt = 0; rt < 2; ++rt)
        #pragma unroll
        for (int nt = 0; nt < 4; ++nt) accO[rt][nt] = 0;

    // drain Qreg loads before the counted staging stream starts
    asm volatile("s_waitcnt vmcnt(0)" ::: "memory");

    // ---- prologue (issue order defines vmcnt counts): K0(8), srel0(1), V0(8)
    #pragma unroll
    for (int u = 0; u < 8; ++u) {
        async_ld16(kptr[u], Klds + (wid * 8 + u) * 512);
        kptr[u] += 64 * DKK;
    }
    __builtin_amdgcn_sched_barrier(0);
    int srow = i0 + (tid >> 3), ssg = tid & 7;
    bf16x8 srelCur = *(const bf16x8*)(Sb + (size_t)srow * LL + ssg * 8);
    const bf16* sPtr = Sb + (size_t)srow * LL + ssg * 8 + 64;
    __builtin_amdgcn_sched_barrier(0);
    #pragma unroll
    for (int u = 0; u < 8; ++u) {
        async_ld16(vptr[u], Vlds + (wid * 8 + u) * 512);
        vptr[u] += 64;
    }

    int jrow = wid * 16 + l15;

    for (int j0 = 0; j0 < LL; j0 += 64) {
        bool notlast = (j0 + 64 < LL);

        // ===== QK phase =====
        asm volatile("s_waitcnt vmcnt(9)" ::: "memory");   // K(i) staged
        bf16x8 kf[8];
        #pragma unroll
        for (int ks = 0; ks < 8; ++ks) {
            int cp = (ks * 4 + quad + jrow) & 31;
            kf[ks] = *(const bf16x8*)&Klds[jrow * 256 + cp * 8];
        }
        asm volatile("s_waitcnt lgkmcnt(0)" ::: "memory"); // own kf reads done
        __builtin_amdgcn_sched_barrier(0);
        if (notlast) {                                     // K(i+1) in flight
            #pragma unroll
            for (int u = 0; u < 8; ++u) {
                async_ld16(kptr[u], Klds + (wid * 8 + u) * 512);
                kptr[u] += 64 * DKK;
            }
        }
        __builtin_amdgcn_sched_barrier(0);
        bf16x8 srelNext;
        if (notlast) {                                     // srel(i+1) in flight
            srelNext = *(const bf16x8*)sPtr;
            sPtr += 64;
        }
        __builtin_amdgcn_sched_barrier(0);
        f32x4 s0 = 0, s1 = 0;
        __builtin_amdgcn_s_setprio(1);
        #pragma unroll
        for (int ks = 0; ks < 8; ++ks) {
            s0 = __builtin_amdgcn_mfma_f32_16x16x32_bf16(Qreg[0][ks], kf[ks], s0, 0, 0, 0);
            s1 = __builtin_amdgcn_mfma_f32_16x16x32_bf16(Qreg[1][ks], kf[ks], s1, 0, 0, 0);
        }
        __builtin_amdgcn_s_setprio(0);
        #pragma unroll
        for (int r = 0; r < 4; ++r) {
            Ss[quad * 4 + r][wid * 16 + l15]      = s0[r];
            Ss[16 + quad * 4 + r][wid * 16 + l15] = s1[r];
        }
        asm volatile("s_waitcnt lgkmcnt(0)\ns_barrier" ::: "memory");   // b2: Ss handoff

        // ===== softmax =====
        {
            int r = tid >> 3, sg = tid & 7;
            int i = i0 + r;
            float v[8];
            #pragma unroll
            for (int c = 0; c < 8; ++c) {
                float sr = (j0 + sg * 8 + c == i + 1) ? 0.f : (float)srelCur[c];
                v[c] = (Ss[r][sg * 8 + c] + sr) * 0.0625f;
            }
            float tmax = v[0];
            #pragma unroll
            for (int c = 1; c < 8; ++c) tmax = fmaxf(tmax, v[c]);
            tmax = fmaxf(tmax, __shfl_xor(tmax, 1));
            tmax = fmaxf(tmax, __shfl_xor(tmax, 2));
            tmax = fmaxf(tmax, __shfl_xor(tmax, 4));
            float mOld = mSt[r], lOld = lSt[r];
            float mNew = fmaxf(mOld, tmax);
            float alpha = __expf(mOld - mNew);
            float ps = 0.f;
            bf16x8 pv;
            #pragma unroll
            for (int c = 0; c < 8; ++c) {
                float p = __expf(v[c] - mNew);
                ps += p;
                pv[c] = (bf16)p;
            }
            ps += __shfl_xor(ps, 1);
            ps += __shfl_xor(ps, 2);
            ps += __shfl_xor(ps, 4);
            *(bf16x8*)&Ps[r][sg * 8] = pv;
            if (sg == 0) { mSt[r] = mNew; lSt[r] = alpha * lOld + ps; aSt[r] = alpha; }
        }
        srelCur = srelNext;
        asm volatile("s_waitcnt lgkmcnt(0)\ns_barrier" ::: "memory");   // b3: Ps handoff

        // ===== PV phase =====
        if (notlast) asm volatile("s_waitcnt vmcnt(9)" ::: "memory");   // V(i) staged
        else         asm volatile("s_waitcnt vmcnt(0)" ::: "memory");
        bf16x8 aF[2][2];
        #pragma unroll
        for (int rt = 0; rt < 2; ++rt)
            #pragma unroll
            for (int kk = 0; kk < 2; ++kk)
                aF[rt][kk] = *(const bf16x8*)&Ps[rt * 16 + l15][kk * 32 + quad * 8];
        float ar[2][4];
        #pragma unroll
        for (int rt = 0; rt < 2; ++rt)
            #pragma unroll
            for (int r = 0; r < 4; ++r) ar[rt][r] = aSt[rt * 16 + quad * 4 + r];
        bf16x8 vf[4][2];
        #pragma unroll
        for (int nt = 0; nt < 4; ++nt) {
            int dd = wid * 64 + nt * 16 + l15;
            int c0 = (quad + dd) & 7;
            int c1 = (4 + quad + dd) & 7;
            vf[nt][0] = *(const bf16x8*)&Vlds[dd * 64 + c0 * 8];
            vf[nt][1] = *(const bf16x8*)&Vlds[dd * 64 + c1 * 8];
        }
        asm volatile("s_waitcnt lgkmcnt(0)" ::: "memory"); // own Ps/vf reads done
        __builtin_amdgcn_sched_barrier(0);
        if (notlast) {                                     // V(i+1) in flight
            #pragma unroll
            for (int u = 0; u < 8; ++u) {
                async_ld16(vptr[u], Vlds + (wid * 8 + u) * 512);
                vptr[u] += 64;
            }
        }
        __builtin_amdgcn_sched_barrier(0);
        __builtin_amdgcn_s_setprio(1);
        #pragma unroll
        for (int nt = 0; nt < 4; ++nt) {
            #pragma unroll
            for (int rt = 0; rt < 2; ++rt) {
                f32x4 o = accO[rt][nt];
                o[0] *= ar[rt][0]; o[1] *= ar[rt][1];
                o[2] *= ar[rt][2]; o[3] *= ar[rt][3];
                o = __builtin_amdgcn_mfma_f32_16x16x32_bf16(aF[rt][0], vf[nt][0], o, 0, 0, 0);
                o = __builtin_amdgcn_mfma_f32_16x16x32_bf16(aF[rt][1], vf[nt][1], o, 0, 0, 0);
                accO[rt][nt] = o;
            }
        }
        __builtin_amdgcn_s_setprio(0);
        // no trailing barrier: Ss WAR covered by b3(i), Ps/aSt WAR by b2(i+1)
    }
    float lr[2][4];
    #pragma unroll
    for (int rt = 0; rt < 2; ++rt)
        #pragma unroll
        for (int r = 0; r < 4; ++r) lr[rt][r] = 1.f / lSt[rt * 16 + quad * 4 + r];
    #pragma unroll
    for (int rt = 0; rt < 2; ++rt)
        #pragma unroll
        for (int nt = 0; nt < 4; ++nt)
            #pragma unroll
            for (int r = 0; r < 4; ++r) {
                int i = i0 + rt * 16 + quad * 4 + r;
                int d = dh * 256 + wid * 64 + nt * 16 + l15;
                out[((size_t)b * LL + i) * DD + d] = accO[rt][nt][r] * lr[rt][r];
            }
}

extern "C" void kernel_launch(void* const* d_in, const int* in_sizes, int n_in,
                              void* d_out, int out_size, void* d_ws, size_t ws_size,
                              hipStream_t stream) {
    const float* inQ = (const float*)d_in[0];
    const float* inK = (const float*)d_in[1];
    const float* inV = (const float*)d_in[2];
    const float* Wq  = (const float*)d_in[3];
    const float* Wk  = (const float*)d_in[4];
    const float* Wv  = (const float*)d_in[5];
    const float* E   = (const float*)d_in[6];
    float* out = (float*)d_out;

    char* ws = (char*)d_ws;
    bf16* Qw   = (bf16*)(ws);                         // 4 MB  [B*L][DK]
    bf16* Kw   = (bf16*)(ws + ((size_t)4  << 20));    // 4 MB  [B*L][DK]
    bf16* Vt   = (bf16*)(ws + ((size_t)8  << 20));    // 8 MB  [D][B*L]
    bf16* SrelW= (bf16*)(ws + ((size_t)16 << 20));    // 32 MB [B,L,L] skewed
    bf16* Xq   = (bf16*)(ws + ((size_t)16 << 20));    // 8 MB  (transient)
    bf16* Xk   = (bf16*)(ws + ((size_t)24 << 20));    // 8 MB
    bf16* Xv   = (bf16*)(ws + ((size_t)32 << 20));    // 8 MB
    bf16* WqT  = (bf16*)(ws + ((size_t)48 << 20));            // [DK][D]
    bf16* WkT  = (bf16*)(ws + ((size_t)48 << 20) + 262144);   // [DK][D]
    bf16* WvT  = (bf16*)(ws + ((size_t)48 << 20) + 524288);   // [D][D]
    bf16* Eb   = (bf16*)(ws + ((size_t)49 << 20));            // [L][DK]

    conv3_f32_bf16<<<dim3(4096, 3), 256, 0, stream>>>(inQ, inK, inV, Xq, Xk, Xv,
                                                      (BB * LL * DD) / 4);
    prep_misc<<<dim3(1024, 4), 256, 0, stream>>>(E, Wq, Wk, Wv, Eb, WqT, WkT, WvT);

    // Q, K, V projections in ONE full-GPU launch (512 blocks)
    gemm_qkv<<<512, 256, 0, stream>>>(Xq, WqT, Qw, Xk, WkT, Kw, Xv, WvT, Vt);
    // Srel (skewed) = skew(Q·E^T): per-batch M=N=2048 K=256
    gemm_srel<<<dim3(16 * 16, BB), 256, 0, stream>>>(Qw, Eb, SrelW,
                                                     (long)LL * DKK, (long)LL * LL);
    attn_kernel<<<dim3(BB * 64 * 2), 256, 0, stream>>>(Qw, Kw, Vt, SrelW, out);
}

// Round 11
// 211.636 us; speedup vs baseline: 1.1697x; 1.0474x over previous
//
#include <hip/hip_runtime.h>
#include <hip/hip_bf16.h>

#define BB 4
#define LL 2048
#define DD 512
#define DKK 256

typedef __bf16 bf16;
typedef __bf16 bf16x4 __attribute__((ext_vector_type(4)));
typedef __bf16 bf16x8 __attribute__((ext_vector_type(8)));
typedef float f32x4 __attribute__((ext_vector_type(4)));

__device__ __forceinline__ void async_ld16(const bf16* g, bf16* l) {
    __builtin_amdgcn_global_load_lds(
        (const __attribute__((address_space(1))) void*)g,
        (__attribute__((address_space(3))) void*)l, 16, 0, 0);
}

// R18: ALL prep work (3 activation convs + E conv + 3 weight transposes) in
// one flat-grid launch.  Region map (blocks of 256 threads):
//   [0,12288)      : Xq/Xk/Xv f32->bf16 (4096 blocks each, exact cover)
//   [12288,12800)  : E f32->bf16 (512)
//   [12800,13312)  : WqT (512)   [13312,13824): WkT (512)   [13824,14848): WvT (1024)
__global__ void prep_all(const float* __restrict__ inQ, const float* __restrict__ inK,
                         const float* __restrict__ inV, const float* __restrict__ E,
                         const float* __restrict__ Wq, const float* __restrict__ Wk,
                         const float* __restrict__ Wv,
                         bf16* __restrict__ Xq, bf16* __restrict__ Xk,
                         bf16* __restrict__ Xv, bf16* __restrict__ Eb,
                         bf16* __restrict__ WqT, bf16* __restrict__ WkT,
                         bf16* __restrict__ WvT)
{
    int bid = blockIdx.x;
    int t = threadIdx.x;
    if (bid < 12288) {
        int region = bid >> 12;
        int i = (bid & 4095) * 256 + t;            // 4096*256 == (B*L*D)/4 exact
        const float* in = (region == 0) ? inQ : (region == 1) ? inK : inV;
        bf16* out = (region == 0) ? Xq : (region == 1) ? Xk : Xv;
        f32x4 v = *(const f32x4*)(in + (size_t)i * 4);
        bf16x4 o;
        #pragma unroll
        for (int j = 0; j < 4; ++j) o[j] = (bf16)v[j];
        *(bf16x4*)(out + (size_t)i * 4) = o;
    } else if (bid < 12800) {
        int i = (bid - 12288) * 256 + t;           // 512*256 == (L*DK)/4 exact
        f32x4 v = *(const f32x4*)(E + (size_t)i * 4);
        bf16x4 o;
        #pragma unroll
        for (int j = 0; j < 4; ++j) o[j] = (bf16)v[j];
        *(bf16x4*)(Eb + (size_t)i * 4) = o;
    } else if (bid < 13312) {
        int idx = (bid - 12800) * 256 + t;         // 512*256 == DD*DKK exact
        int r = idx / DKK, c = idx % DKK;
        WqT[(size_t)c * DD + r] = (bf16)Wq[idx];
    } else if (bid < 13824) {
        int idx = (bid - 13312) * 256 + t;
        int r = idx / DKK, c = idx % DKK;
        WkT[(size_t)c * DD + r] = (bf16)Wk[idx];
    } else {
        int idx = (bid - 13824) * 256 + t;         // 1024*256 == DD*DD exact
        int r = idx / DD, c = idx % DD;
        WvT[(size_t)c * DD + r] = (bf16)Wv[idx];
    }
}

// Merged Q/K/V projection GEMM, R18: K-step double-buffer with ONE-AHEAD
// staging.  Buffer p^1 is staged (8 async_ld16/wave) BEFORE computing step i
// from buffer p; the single __syncthreads at step end (drains own vmcnt+lgkm)
// publishes the staged data AND guards WAR.  Staging latency (~300-500cy L2)
// now hides under the 32-MFMA compute phase instead of being serially exposed
// (R17: stage -> sync -> compute each step).  One barrier per BK=64 step.
// LDS 64KB -> 2 blocks/CU.  tbuf (mode-2 transpose bounce) ALIASES Als[0]:
// nsteps=8 even -> last compute reads buf 1; Als[0] dead at epilogue.
__launch_bounds__(256, 2)
__global__ void gemm_qkv(const bf16* __restrict__ Xq, const bf16* __restrict__ WqT,
                         bf16* __restrict__ Qw,
                         const bf16* __restrict__ Xk, const bf16* __restrict__ WkT,
                         bf16* __restrict__ Kw,
                         const bf16* __restrict__ Xv, const bf16* __restrict__ WvT,
                         bf16* __restrict__ Vt)
{
    __shared__ bf16 Als[2][2][128 * 32];   // [buf][sub][...]  32 KB
    __shared__ bf16 Bls[2][2][128 * 32];   // 32 KB

    int tid  = threadIdx.x;
    int lane = tid & 63;
    int wid  = tid >> 6;
    int l15  = lane & 15;
    int quad = lane >> 4;

    int bid  = blockIdx.x;
    int mode = (bid < 128) ? 0 : (bid < 256) ? 1 : 2;
    int idx  = bid - ((mode == 0) ? 0 : (mode == 1) ? 128 : 256);
    int nb   = (mode == 2) ? 4 : 2;
    int gx = idx % nb;
    int gy = idx / nb;
    int N  = (mode == 2) ? DD : DKK;
    const bf16* A  = (mode == 0) ? Xq  : (mode == 1) ? Xk  : Xv;
    const bf16* Bw = (mode == 0) ? WqT : (mode == 1) ? WkT : WvT;
    const int K = DD;

    const bf16* Ab = A + (size_t)gy * 128 * K;
    const bf16* Bb = Bw + (size_t)gx * 128 * K;

    int rl = lane >> 2;
    int sl = lane & 3;
    int half = wid & 1;
    const bf16* gsrc = (wid < 2) ? Ab : Bb;
    bf16 (*ls)[2][128 * 32] = (wid < 2) ? Als : Bls;   // this wave's staging dest

    const bf16* gptr[4];
    #pragma unroll
    for (int u = 0; u < 4; ++u) {
        int inst = half * 4 + u;
        int row  = inst * 16 + rl;
        int c    = (sl - (row >> 1)) & 3;
        gptr[u] = gsrc + (size_t)row * K + c * 8;
    }

#define STAGE_G(P) do {                                                    \
    _Pragma("unroll")                                                      \
    for (int u_ = 0; u_ < 4; ++u_) {                                       \
        async_ld16(gptr[u_],      &ls[P][0][(half * 4 + u_) * 512]);       \
        async_ld16(gptr[u_] + 32, &ls[P][1][(half * 4 + u_) * 512]);       \
        gptr[u_] += 64;                                                    \
    } } while (0)

    f32x4 acc[4][4];
    #pragma unroll
    for (int i = 0; i < 4; ++i)
        #pragma unroll
        for (int j = 0; j < 4; ++j) acc[i][j] = 0;

    const int nsteps = K / 64;   // 8 (even: tbuf aliasing of Als[0] is safe)
    STAGE_G(0);
    __syncthreads();
    for (int s = 0; s < nsteps; ++s) {
        int cur = s & 1;
        if (s + 1 < nsteps) STAGE_G(cur ^ 1);      // one-ahead, in flight
        #pragma unroll
        for (int h2 = 0; h2 < 2; ++h2) {
            bf16x8 fA[4], fB[4];
            #pragma unroll
            for (int rt = 0; rt < 4; ++rt) {
                int row = (wid & 1) * 64 + rt * 16 + l15;
                int sx  = (quad + (row >> 1)) & 3;
                fA[rt] = *(const bf16x8*)&Als[cur][h2][row * 32 + sx * 8];
            }
            #pragma unroll
            for (int ct = 0; ct < 4; ++ct) {
                int col = (wid >> 1) * 64 + ct * 16 + l15;
                int sx  = (quad + (col >> 1)) & 3;
                fB[ct] = *(const bf16x8*)&Bls[cur][h2][col * 32 + sx * 8];
            }
            #pragma unroll
            for (int rt = 0; rt < 4; ++rt)
                #pragma unroll
                for (int ct = 0; ct < 4; ++ct)
                    acc[rt][ct] = __builtin_amdgcn_mfma_f32_16x16x32_bf16(
                                      fA[rt], fB[ct], acc[rt][ct], 0, 0, 0);
        }
        if (s + 1 < nsteps || mode == 2) __syncthreads();
        // (modes 0/1: register epilogue, no LDS reuse -> last barrier skipped)
    }
#undef STAGE_G

    if (mode == 2) {
        // C^T -> Vt[n][m] via tbuf bounce; tbuf aliases Als[0] (17.4KB <= 32KB)
        bf16* tbuf = &Als[0][0][0];
        #pragma unroll
        for (int p = 0; p < 2; ++p) {
            if ((wid >> 1) == p) {
                #pragma unroll
                for (int rt = 0; rt < 4; ++rt)
                    #pragma unroll
                    for (int ct = 0; ct < 4; ++ct)
                        #pragma unroll
                        for (int r = 0; r < 4; ++r)
                            tbuf[(ct * 16 + l15) * 136
                                 + (wid & 1) * 64 + rt * 16 + quad * 4 + r]
                                = (bf16)acc[rt][ct][r];
            }
            __syncthreads();
            int row = tid >> 2, c0 = (tid & 3) * 32;
            bf16* dst = Vt + (size_t)(gx * 128 + p * 64 + row) * (BB * LL)
                           + (size_t)gy * 128 + c0;
            #pragma unroll
            for (int q = 0; q < 4; ++q)
                *(bf16x8*)(dst + q * 8) = *(const bf16x8*)&tbuf[row * 136 + c0 + q * 8];
            __syncthreads();
        }
    } else {
        bf16* Cb = (mode == 0) ? Qw : Kw;
        int m0 = gy * 128 + (wid & 1) * 64;
        int n0 = gx * 128 + (wid >> 1) * 64;
        #pragma unroll
        for (int rt = 0; rt < 4; ++rt)
            #pragma unroll
            for (int ct = 0; ct < 4; ++ct)
                #pragma unroll
                for (int r = 0; r < 4; ++r) {
                    int m = m0 + rt * 16 + quad * 4 + r;
                    int n = n0 + ct * 16 + l15;
                    Cb[(size_t)m * N + n] = (bf16)acc[rt][ct][r];
                }
    }
}

// Srel GEMM, R18: same K-step double-buffer one-ahead staging (4 steps at
// K=256, 1 barrier each, staging hidden under compute).  Skewed scatter
// epilogue unchanged (register-sourced, no LDS -> last barrier skipped).
__launch_bounds__(256, 2)
__global__ void gemm_srel(const bf16* __restrict__ A, const bf16* __restrict__ B,
                          bf16* __restrict__ C, long aStride, long cStride)
{
    __shared__ bf16 Als[2][2][128 * 32];
    __shared__ bf16 Bls[2][2][128 * 32];

    int tid  = threadIdx.x;
    int lane = tid & 63;
    int wid  = tid >> 6;
    int l15  = lane & 15;
    int quad = lane >> 4;
    const int N = LL, K = DKK;
    int nb = N >> 7;
    int gx = blockIdx.x % nb;
    int gy = blockIdx.x / nb;

    const bf16* Ab = A + (size_t)blockIdx.y * aStride + (size_t)gy * 128 * K;
    const bf16* Bb = B + (size_t)gx * 128 * K;

    int rl = lane >> 2;
    int sl = lane & 3;
    int half = wid & 1;
    const bf16* gsrc = (wid < 2) ? Ab : Bb;
    bf16 (*ls)[2][128 * 32] = (wid < 2) ? Als : Bls;

    const bf16* gptr[4];
    #pragma unroll
    for (int u = 0; u < 4; ++u) {
        int inst = half * 4 + u;
        int row  = inst * 16 + rl;
        int c    = (sl - (row >> 1)) & 3;
        gptr[u] = gsrc + (size_t)row * K + c * 8;
    }

#define STAGE_S(P) do {                                                    \
    _Pragma("unroll")                                                      \
    for (int u_ = 0; u_ < 4; ++u_) {                                       \
        async_ld16(gptr[u_],      &ls[P][0][(half * 4 + u_) * 512]);       \
        async_ld16(gptr[u_] + 32, &ls[P][1][(half * 4 + u_) * 512]);       \
        gptr[u_] += 64;                                                    \
    } } while (0)

    f32x4 acc[4][4];
    #pragma unroll
    for (int i = 0; i < 4; ++i)
        #pragma unroll
        for (int j = 0; j < 4; ++j) acc[i][j] = 0;

    const int nsteps = K / 64;   // 4
    STAGE_S(0);
    __syncthreads();
    for (int s = 0; s < nsteps; ++s) {
        int cur = s & 1;
        if (s + 1 < nsteps) STAGE_S(cur ^ 1);
        #pragma unroll
        for (int h2 = 0; h2 < 2; ++h2) {
            bf16x8 fA[4], fB[4];
            #pragma unroll
            for (int rt = 0; rt < 4; ++rt) {
                int row = (wid & 1) * 64 + rt * 16 + l15;
                int sx  = (quad + (row >> 1)) & 3;
                fA[rt] = *(const bf16x8*)&Als[cur][h2][row * 32 + sx * 8];
            }
            #pragma unroll
            for (int ct = 0; ct < 4; ++ct) {
                int col = (wid >> 1) * 64 + ct * 16 + l15;
                int sx  = (quad + (col >> 1)) & 3;
                fB[ct] = *(const bf16x8*)&Bls[cur][h2][col * 32 + sx * 8];
            }
            #pragma unroll
            for (int rt = 0; rt < 4; ++rt)
                #pragma unroll
                for (int ct = 0; ct < 4; ++ct)
                    acc[rt][ct] = __builtin_amdgcn_mfma_f32_16x16x32_bf16(
                                      fA[rt], fB[ct], acc[rt][ct], 0, 0, 0);
        }
        if (s + 1 < nsteps) __syncthreads();
    }
#undef STAGE_S

    bf16* Cb = C + (size_t)blockIdx.y * cStride;
    int m0 = gy * 128 + (wid & 1) * 64;
    int n0 = gx * 128 + (wid >> 1) * 64;
    #pragma unroll
    for (int rt = 0; rt < 4; ++rt)
        #pragma unroll
        for (int ct = 0; ct < 4; ++ct)
            #pragma unroll
            for (int r = 0; r < 4; ++r) {
                int row = m0 + rt * 16 + quad * 4 + r;
                int c   = n0 + ct * 16 + l15;
                bool lower = (c >= LL - 1 - row);
                int dr = lower ? row : row - 1;
                int dc = lower ? c - (LL - 1 - row) : c + row + 1;
                if (lower || row >= 1)
                    Cb[(size_t)dr * LL + dc] = (bf16)acc[rt][ct][r];
            }
}

// Fused attention: R13 structure (best-measured, 85.5us) -- untouched.
// 4 waves / 256 threads, one-ahead split staging with counted vmcnt,
// pointer-increment staging addresses, Ss-LDS softmax.
__launch_bounds__(256, 2)
__global__ void attn_kernel(const bf16* __restrict__ Qw, const bf16* __restrict__ Kw,
                            const bf16* __restrict__ Vt, const bf16* __restrict__ Srel,
                            float* __restrict__ out)
{
    __shared__ bf16  Klds[64 * 256];      // rows j (64), 32 chunks of 8, rotated
    __shared__ bf16  Vlds[256 * 64];      // rows d (256), 8 chunks of 8, rotated
    __shared__ float Ss[32][68];
    __shared__ bf16  Ps[32][72];
    __shared__ float mSt[32], lSt[32], aSt[32];

    int tid  = threadIdx.x;
    int lane = tid & 63;
    int wid  = tid >> 6;
    int l15  = lane & 15;
    int quad = lane >> 4;

    int xcd = blockIdx.x & 7;          // XCD = blockIdx % 8 (round-robin dispatch)
    int b   = xcd >> 1;
    int dh  = xcd & 1;
    int i0  = (blockIdx.x >> 3) * 32;

    const bf16* Qb = Qw + (size_t)b * LL * DKK;
    const bf16* Kb = Kw + (size_t)b * LL * DKK;
    const bf16* Sb = Srel + (size_t)b * LL * LL;
    const bf16* Vb = Vt + (size_t)(dh * 256) * (BB * LL) + (size_t)b * LL;

    // persistent staging pointers (wave-local rows), bumped per iteration
    const bf16* kptr[8];
    const bf16* vptr[8];
    #pragma unroll
    for (int u = 0; u < 8; ++u) {
        int inst = wid * 8 + u;
        int j_ = inst * 2 + (lane >> 5);
        int ck = ((lane & 31) - j_) & 31;
        kptr[u] = Kb + (size_t)j_ * DKK + ck * 8;
        int d_ = inst * 8 + (lane >> 3);
        int cv = ((lane & 7) - d_) & 7;
        vptr[u] = Vb + (size_t)d_ * (BB * LL) + cv * 8;
    }

    bf16x8 Qreg[2][8];
    #pragma unroll
    for (int rt = 0; rt < 2; ++rt)
        #pragma unroll
        for (int ks = 0; ks < 8; ++ks)
            Qreg[rt][ks] = *(const bf16x8*)(Qb + (size_t)(i0 + rt * 16 + l15) * DKK
                                            + ks * 32 + quad * 8);

    if (tid < 32) { mSt[tid] = -1e30f; lSt[tid] = 0.f; }

    f32x4 accO[2][4];
    #pragma unroll
    for (int rt = 0; rt < 2; ++rt)
        #pragma unroll
        for (int nt = 0; nt < 4; ++nt) accO[rt][nt] = 0;

    // drain Qreg loads before the counted staging stream starts
    asm volatile("s_waitcnt vmcnt(0)" ::: "memory");

    // ---- prologue (issue order defines vmcnt counts): K0(8), srel0(1), V0(8)
    #pragma unroll
    for (int u = 0; u < 8; ++u) {
        async_ld16(kptr[u], Klds + (wid * 8 + u) * 512);
        kptr[u] += 64 * DKK;
    }
    __builtin_amdgcn_sched_barrier(0);
    int srow = i0 + (tid >> 3), ssg = tid & 7;
    bf16x8 srelCur = *(const bf16x8*)(Sb + (size_t)srow * LL + ssg * 8);
    const bf16* sPtr = Sb + (size_t)srow * LL + ssg * 8 + 64;
    __builtin_amdgcn_sched_barrier(0);
    #pragma unroll
    for (int u = 0; u < 8; ++u) {
        async_ld16(vptr[u], Vlds + (wid * 8 + u) * 512);
        vptr[u] += 64;
    }

    int jrow = wid * 16 + l15;

    for (int j0 = 0; j0 < LL; j0 += 64) {
        bool notlast = (j0 + 64 < LL);

        // ===== QK phase =====
        asm volatile("s_waitcnt vmcnt(9)" ::: "memory");   // K(i) staged
        bf16x8 kf[8];
        #pragma unroll
        for (int ks = 0; ks < 8; ++ks) {
            int cp = (ks * 4 + quad + jrow) & 31;
            kf[ks] = *(const bf16x8*)&Klds[jrow * 256 + cp * 8];
        }
        asm volatile("s_waitcnt lgkmcnt(0)" ::: "memory"); // own kf reads done
        __builtin_amdgcn_sched_barrier(0);
        if (notlast) {                                     // K(i+1) in flight
            #pragma unroll
            for (int u = 0; u < 8; ++u) {
                async_ld16(kptr[u], Klds + (wid * 8 + u) * 512);
                kptr[u] += 64 * DKK;
            }
        }
        __builtin_amdgcn_sched_barrier(0);
        bf16x8 srelNext;
        if (notlast) {                                     // srel(i+1) in flight
            srelNext = *(const bf16x8*)sPtr;
            sPtr += 64;
        }
        __builtin_amdgcn_sched_barrier(0);
        f32x4 s0 = 0, s1 = 0;
        __builtin_amdgcn_s_setprio(1);
        #pragma unroll
        for (int ks = 0; ks < 8; ++ks) {
            s0 = __builtin_amdgcn_mfma_f32_16x16x32_bf16(Qreg[0][ks], kf[ks], s0, 0, 0, 0);
            s1 = __builtin_amdgcn_mfma_f32_16x16x32_bf16(Qreg[1][ks], kf[ks], s1, 0, 0, 0);
        }
        __builtin_amdgcn_s_setprio(0);
        #pragma unroll
        for (int r = 0; r < 4; ++r) {
            Ss[quad * 4 + r][wid * 16 + l15]      = s0[r];
            Ss[16 + quad * 4 + r][wid * 16 + l15] = s1[r];
        }
        asm volatile("s_waitcnt lgkmcnt(0)\ns_barrier" ::: "memory");   // b2: Ss handoff

        // ===== softmax =====
        {
            int r = tid >> 3, sg = tid & 7;
            int i = i0 + r;
            float v[8];
            #pragma unroll
            for (int c = 0; c < 8; ++c) {
                float sr = (j0 + sg * 8 + c == i + 1) ? 0.f : (float)srelCur[c];
                v[c] = (Ss[r][sg * 8 + c] + sr) * 0.0625f;
            }
            float tmax = v[0];
            #pragma unroll
            for (int c = 1; c < 8; ++c) tmax = fmaxf(tmax, v[c]);
            tmax = fmaxf(tmax, __shfl_xor(tmax, 1));
            tmax = fmaxf(tmax, __shfl_xor(tmax, 2));
            tmax = fmaxf(tmax, __shfl_xor(tmax, 4));
            float mOld = mSt[r], lOld = lSt[r];
            float mNew = fmaxf(mOld, tmax);
            float alpha = __expf(mOld - mNew);
            float ps = 0.f;
            bf16x8 pv;
            #pragma unroll
            for (int c = 0; c < 8; ++c) {
                float p = __expf(v[c] - mNew);
                ps += p;
                pv[c] = (bf16)p;
            }
            ps += __shfl_xor(ps, 1);
            ps += __shfl_xor(ps, 2);
            ps += __shfl_xor(ps, 4);
            *(bf16x8*)&Ps[r][sg * 8] = pv;
            if (sg == 0) { mSt[r] = mNew; lSt[r] = alpha * lOld + ps; aSt[r] = alpha; }
        }
        srelCur = srelNext;
        asm volatile("s_waitcnt lgkmcnt(0)\ns_barrier" ::: "memory");   // b3: Ps handoff

        // ===== PV phase =====
        if (notlast) asm volatile("s_waitcnt vmcnt(9)" ::: "memory");   // V(i) staged
        else         asm volatile("s_waitcnt vmcnt(0)" ::: "memory");
        bf16x8 aF[2][2];
        #pragma unroll
        for (int rt = 0; rt < 2; ++rt)
            #pragma unroll
            for (int kk = 0; kk < 2; ++kk)
                aF[rt][kk] = *(const bf16x8*)&Ps[rt * 16 + l15][kk * 32 + quad * 8];
        float ar[2][4];
        #pragma unroll
        for (int rt = 0; rt < 2; ++rt)
            #pragma unroll
            for (int r = 0; r < 4; ++r) ar[rt][r] = aSt[rt * 16 + quad * 4 + r];
        bf16x8 vf[4][2];
        #pragma unroll
        for (int nt = 0; nt < 4; ++nt) {
            int dd = wid * 64 + nt * 16 + l15;
            int c0 = (quad + dd) & 7;
            int c1 = (4 + quad + dd) & 7;
            vf[nt][0] = *(const bf16x8*)&Vlds[dd * 64 + c0 * 8];
            vf[nt][1] = *(const bf16x8*)&Vlds[dd * 64 + c1 * 8];
        }
        asm volatile("s_waitcnt lgkmcnt(0)" ::: "memory"); // own Ps/vf reads done
        __builtin_amdgcn_sched_barrier(0);
        if (notlast) {                                     // V(i+1) in flight
            #pragma unroll
            for (int u = 0; u < 8; ++u) {
                async_ld16(vptr[u], Vlds + (wid * 8 + u) * 512);
                vptr[u] += 64;
            }
        }
        __builtin_amdgcn_sched_barrier(0);
        __builtin_amdgcn_s_setprio(1);
        #pragma unroll
        for (int nt = 0; nt < 4; ++nt) {
            #pragma unroll
            for (int rt = 0; rt < 2; ++rt) {
                f32x4 o = accO[rt][nt];
                o[0] *= ar[rt][0]; o[1] *= ar[rt][1];
                o[2] *= ar[rt][2]; o[3] *= ar[rt][3];
                o = __builtin_amdgcn_mfma_f32_16x16x32_bf16(aF[rt][0], vf[nt][0], o, 0, 0, 0);
                o = __builtin_amdgcn_mfma_f32_16x16x32_bf16(aF[rt][1], vf[nt][1], o, 0, 0, 0);
                accO[rt][nt] = o;
            }
        }
        __builtin_amdgcn_s_setprio(0);
        // no trailing barrier: Ss WAR covered by b3(i), Ps/aSt WAR by b2(i+1)
    }
    float lr[2][4];
    #pragma unroll
    for (int rt = 0; rt < 2; ++rt)
        #pragma unroll
        for (int r = 0; r < 4; ++r) lr[rt][r] = 1.f / lSt[rt * 16 + quad * 4 + r];
    #pragma unroll
    for (int rt = 0; rt < 2; ++rt)
        #pragma unroll
        for (int nt = 0; nt < 4; ++nt)
            #pragma unroll
            for (int r = 0; r < 4; ++r) {
                int i = i0 + rt * 16 + quad * 4 + r;
                int d = dh * 256 + wid * 64 + nt * 16 + l15;
                out[((size_t)b * LL + i) * DD + d] = accO[rt][nt][r] * lr[rt][r];
            }
}

extern "C" void kernel_launch(void* const* d_in, const int* in_sizes, int n_in,
                              void* d_out, int out_size, void* d_ws, size_t ws_size,
                              hipStream_t stream) {
    const float* inQ = (const float*)d_in[0];
    const float* inK = (const float*)d_in[1];
    const float* inV = (const float*)d_in[2];
    const float* Wq  = (const float*)d_in[3];
    const float* Wk  = (const float*)d_in[4];
    const float* Wv  = (const float*)d_in[5];
    const float* E   = (const float*)d_in[6];
    float* out = (float*)d_out;

    char* ws = (char*)d_ws;
    bf16* Qw   = (bf16*)(ws);                         // 4 MB  [B*L][DK]
    bf16* Kw   = (bf16*)(ws + ((size_t)4  << 20));    // 4 MB  [B*L][DK]
    bf16* Vt   = (bf16*)(ws + ((size_t)8  << 20));    // 8 MB  [D][B*L]
    bf16* SrelW= (bf16*)(ws + ((size_t)16 << 20));    // 32 MB [B,L,L] skewed
    bf16* Xq   = (bf16*)(ws + ((size_t)16 << 20));    // 8 MB  (transient)
    bf16* Xk   = (bf16*)(ws + ((size_t)24 << 20));    // 8 MB
    bf16* Xv   = (bf16*)(ws + ((size_t)32 << 20));    // 8 MB
    bf16* WqT  = (bf16*)(ws + ((size_t)48 << 20));            // [DK][D]
    bf16* WkT  = (bf16*)(ws + ((size_t)48 << 20) + 262144);   // [DK][D]
    bf16* WvT  = (bf16*)(ws + ((size_t)48 << 20) + 524288);   // [D][D]
    bf16* Eb   = (bf16*)(ws + ((size_t)49 << 20));            // [L][DK]

    // all prep (3 activation convs + E conv + 3 weight transposes): one launch
    prep_all<<<14848, 256, 0, stream>>>(inQ, inK, inV, E, Wq, Wk, Wv,
                                        Xq, Xk, Xv, Eb, WqT, WkT, WvT);
    // Q, K, V projections in ONE full-GPU launch (512 blocks)
    gemm_qkv<<<512, 256, 0, stream>>>(Xq, WqT, Qw, Xk, WkT, Kw, Xv, WvT, Vt);
    // Srel (skewed) = skew(Q·E^T): per-batch M=N=2048 K=256
    gemm_srel<<<dim3(16 * 16, BB), 256, 0, stream>>>(Qw, Eb, SrelW,
                                                     (long)LL * DKK, (long)LL * LL);
    attn_kernel<<<dim3(BB * 64 * 2), 256, 0, stream>>>(Qw, Kw, Vt, SrelW, out);
}